// Round 8
// baseline (174.712 us; speedup 1.0000x reference)
//
#include <hip/hip_runtime.h>

typedef __attribute__((ext_vector_type(8))) short bf16x8;
typedef __attribute__((ext_vector_type(4))) float f32x4;
typedef __attribute__((ext_vector_type(4))) unsigned int u32x4;

#define WIDTH  2048
#define NHEADS 16
#define HDIM   128

__device__ __forceinline__ unsigned short f2bf(float f) {
  union { float f; unsigned int u; } v; v.f = f;
  unsigned int u = v.u;
  unsigned int r = (u + 0x7FFFu + ((u >> 16) & 1u)) >> 16;  // RNE
  return (unsigned short)r;
}

// Prep: transpose w_in/w_a [h][i][j] -> bf16 [h][j][i]; precompute
// 8*softplus(a_param)*log2(e) (so av = exp2(-ga*sp)).
__global__ __launch_bounds__(256) void prep_kernel(
    const float* __restrict__ w_in, const float* __restrict__ w_a,
    const float* __restrict__ a_param,
    unsigned short* __restrict__ wTin, unsigned short* __restrict__ wTa,
    float* __restrict__ sp8) {
  int tid = blockIdx.x * 256 + threadIdx.x;    // 0 .. 16*128*128-1
  int h   = tid >> 14;
  int rem = tid & 16383;
  int j   = rem >> 7;
  int i   = rem & 127;
  int src = (h << 14) + (i << 7) + j;
  wTin[tid] = f2bf(w_in[src]);
  wTa[tid]  = f2bf(w_a[src]);
  if (tid < WIDTH) {
    float v  = a_param[tid];
    float sp = (v > 20.0f) ? v : log1pf(__expf(v));
    sp8[tid] = 8.0f * sp * 1.4426950408889634f;   // * log2(e)
  }
}

// Barrier-free streaming design:
//  - block = 512 threads (8 waves) on one head; weights staged to LDS once.
//  - wave = 16 rows x 32 cols per iteration, 16 iterations (512 rows/block).
//  - x loaded DIRECTLY into MFMA B-fragments (no LDS staging, no barriers),
//    2-deep software pipeline (load i+1 during compute of i).
//  - epilogue x recovered via identity-MFMA transpose (no extra memory).
__global__ __launch_bounds__(512, 4) void rglru_kernel(
    const float* __restrict__ x, const float* __restrict__ state,
    const float* __restrict__ b_in, const float* __restrict__ b_a,
    const unsigned short* __restrict__ wTin, const unsigned short* __restrict__ wTa,
    const float* __restrict__ sp8, float* __restrict__ out) {
  __shared__ unsigned short wlds[2 * HDIM * HDIM];  // 64 KB, XOR-swizzled

  const int t    = threadIdx.x;
  const int lane = t & 63;
  const int l15  = lane & 15;
  const int l4   = lane >> 4;
  const int w    = t >> 6;       // 0..7
  const int rq   = w >> 2;       // 0..1: 16-row group within 32-row stripe
  const int cg   = w & 3;        // 0..3: 32-col group within head

  const int bid = blockIdx.x;
  const int h   = bid & 15;
  const int s   = bid >> 4;      // 0..31

  // ---- stage weights (both ops) into LDS, swizzled; the ONLY barrier ----
  {
    const unsigned short* s0 = wTin + h * HDIM * HDIM;
    const unsigned short* s1 = wTa  + h * HDIM * HDIM;
#pragma unroll
    for (int it = 0; it < 4; ++it) {
      int c  = it * 512 + t;       // 16B chunk id, 0..2047
      int j  = c >> 4;             // weight row (out col) 0..127
      int sl = c & 15;             // 16B slot within row
      int off = (j * 256 + sl * 16) ^ ((j & 7) << 4);
      *reinterpret_cast<u32x4*>(reinterpret_cast<char*>(wlds) + off) =
          *reinterpret_cast<const u32x4*>(s0 + c * 8);
      *reinterpret_cast<u32x4*>(reinterpret_cast<char*>(wlds) + 32768 + off) =
          *reinterpret_cast<const u32x4*>(s1 + c * 8);
    }
  }
  __syncthreads();

  // ---- identity fragments: D = I_shift * B extracts B rows j+16n in D layout ----
  bf16x8 idf0, idf1;
  {
    union { bf16x8 v; unsigned short us[8]; } a, b;
#pragma unroll
    for (int e = 0; e < 8; ++e) {
      int k = l4 * 8 + e;
      a.us[e] = (k == l15)      ? (unsigned short)0x3F80 : (unsigned short)0;
      b.us[e] = (k == l15 + 16) ? (unsigned short)0x3F80 : (unsigned short)0;
    }
    idf0 = a.v; idf1 = b.v;
  }

  const int  colh    = cg * 32;
  const long rowbase = (long)s * 512;
  const float* xh    = x + h * HDIM;

  // per-column constants (reloaded per-iter would cost regs; these are L1-hot)
  const int cb = h * HDIM + colh + l4 * 4;

  // ---- prologue: issue x loads for iter 0 ----
  // x window q covers k-window (cg+q)&3, so xfr[0] is always window cg
  // (static index for the identity transpose).
  f32x4 xf32[8];
#pragma unroll
  for (int q = 0; q < 4; ++q) {
    int kw = (cg + q) & 3;
    const float* p = xh + (rowbase + rq * 16 + l15) * WIDTH + kw * 32 + l4 * 8;
    xf32[q * 2]     = *reinterpret_cast<const f32x4*>(p);
    xf32[q * 2 + 1] = *reinterpret_cast<const f32x4*>(p + 4);
  }

  for (int i = 0; i < 16; ++i) {
    const long row0 = rowbase + i * 32 + rq * 16;

    // convert landed x -> bf16 fragments (frees xf32 for the next prefetch)
    bf16x8 xfr[4];
#pragma unroll
    for (int q = 0; q < 4; ++q) {
      union { bf16x8 v; unsigned int u[4]; } uu;
      f32x4 lo = xf32[q * 2], hi = xf32[q * 2 + 1];
      uu.u[0] = (unsigned)f2bf(lo[0]) | ((unsigned)f2bf(lo[1]) << 16);
      uu.u[1] = (unsigned)f2bf(lo[2]) | ((unsigned)f2bf(lo[3]) << 16);
      uu.u[2] = (unsigned)f2bf(hi[0]) | ((unsigned)f2bf(hi[1]) << 16);
      uu.u[3] = (unsigned)f2bf(hi[2]) | ((unsigned)f2bf(hi[3]) << 16);
      xfr[q] = uu.v;
    }

    // prefetch next tile's x (in flight across this whole iteration)
    if (i + 1 < 16) {
#pragma unroll
      for (int q = 0; q < 4; ++q) {
        int kw = (cg + q) & 3;
        const float* p = xh + (rowbase + (i + 1) * 32 + rq * 16 + l15) * WIDTH
                         + kw * 32 + l4 * 8;
        xf32[q * 2]     = *reinterpret_cast<const f32x4*>(p);
        xf32[q * 2 + 1] = *reinterpret_cast<const f32x4*>(p + 4);
      }
    }

    // state + per-col constants, issued early (consumed after MFMA phase)
    const long ro = (row0 + l15) * WIDTH + h * HDIM + colh + l4 * 4;
    f32x4 sv0 = *reinterpret_cast<const f32x4*>(state + ro);
    f32x4 sv1 = *reinterpret_cast<const f32x4*>(state + ro + 16);
    f32x4 bi0 = *reinterpret_cast<const f32x4*>(b_in + cb);
    f32x4 bi1 = *reinterpret_cast<const f32x4*>(b_in + cb + 16);
    f32x4 ba0 = *reinterpret_cast<const f32x4*>(b_a + cb);
    f32x4 ba1 = *reinterpret_cast<const f32x4*>(b_a + cb + 16);
    f32x4 sp0 = *reinterpret_cast<const f32x4*>(sp8 + cb);
    f32x4 sp1 = *reinterpret_cast<const f32x4*>(sp8 + cb + 16);

    // ---- MFMA phase: weights from LDS, x from registers ----
    f32x4 zero = (f32x4)(0.0f);
    f32x4 xt0 = __builtin_amdgcn_mfma_f32_16x16x32_bf16(idf0, xfr[0], zero, 0, 0, 0);
    f32x4 xt1 = __builtin_amdgcn_mfma_f32_16x16x32_bf16(idf1, xfr[0], zero, 0, 0, 0);
    f32x4 ai0 = zero, ai1 = zero, aa0 = zero, aa1 = zero;
#pragma unroll
    for (int q = 0; q < 4; ++q) {
      int kw = (cg + q) & 3;
      int j0 = colh + l15;
      int j1 = colh + 16 + l15;
      int o0 = (j0 * 256 + kw * 64 + l4 * 16) ^ ((j0 & 7) << 4);
      int o1 = (j1 * 256 + kw * 64 + l4 * 16) ^ ((j1 & 7) << 4);
      bf16x8 wi0 = *reinterpret_cast<const bf16x8*>(
          reinterpret_cast<const char*>(wlds) + o0);
      bf16x8 wi1 = *reinterpret_cast<const bf16x8*>(
          reinterpret_cast<const char*>(wlds) + o1);
      bf16x8 wa0 = *reinterpret_cast<const bf16x8*>(
          reinterpret_cast<const char*>(wlds) + 32768 + o0);
      bf16x8 wa1 = *reinterpret_cast<const bf16x8*>(
          reinterpret_cast<const char*>(wlds) + 32768 + o1);
      ai0 = __builtin_amdgcn_mfma_f32_16x16x32_bf16(wi0, xfr[q], ai0, 0, 0, 0);
      ai1 = __builtin_amdgcn_mfma_f32_16x16x32_bf16(wi1, xfr[q], ai1, 0, 0, 0);
      aa0 = __builtin_amdgcn_mfma_f32_16x16x32_bf16(wa0, xfr[q], aa0, 0, 0, 0);
      aa1 = __builtin_amdgcn_mfma_f32_16x16x32_bf16(wa1, xfr[q], aa1, 0, 0, 0);
    }

    // ---- epilogue: lane = batch row l15, 4 consecutive cols per n ----
    f32x4 o0, o1;
#pragma unroll
    for (int r = 0; r < 4; ++r) {
      {
        float yin = ai0[r] + bi0[r];
        float ya  = aa0[r] + ba0[r];
        float gx  = __builtin_amdgcn_rcpf(1.0f + __expf(-yin));
        float ga  = __builtin_amdgcn_rcpf(1.0f + __expf(-ya));
        float av  = exp2f(-ga * sp0[r]);
        float sc  = sqrtf(fmaxf(1.0f - av * av, 0.0f));
        o0[r] = av * sv0[r] + gx * xt0[r] * sc;
      }
      {
        float yin = ai1[r] + bi1[r];
        float ya  = aa1[r] + ba1[r];
        float gx  = __builtin_amdgcn_rcpf(1.0f + __expf(-yin));
        float ga  = __builtin_amdgcn_rcpf(1.0f + __expf(-ya));
        float av  = exp2f(-ga * sp1[r]);
        float sc  = sqrtf(fmaxf(1.0f - av * av, 0.0f));
        o1[r] = av * sv1[r] + gx * xt1[r] * sc;
      }
    }
    *reinterpret_cast<f32x4*>(out + ro)      = o0;
    *reinterpret_cast<f32x4*>(out + ro + 16) = o1;
  }
}

extern "C" void kernel_launch(void* const* d_in, const int* in_sizes, int n_in,
                              void* d_out, int out_size, void* d_ws, size_t ws_size,
                              hipStream_t stream) {
  const float* x       = (const float*)d_in[0];
  const float* state   = (const float*)d_in[1];
  const float* w_in    = (const float*)d_in[2];
  const float* b_in    = (const float*)d_in[3];
  const float* w_a     = (const float*)d_in[4];
  const float* b_a     = (const float*)d_in[5];
  const float* a_param = (const float*)d_in[6];
  float* out = (float*)d_out;

  unsigned short* wTin = (unsigned short*)d_ws;
  unsigned short* wTa  = wTin + NHEADS * HDIM * HDIM;
  float*          sp8  = (float*)(wTa + NHEADS * HDIM * HDIM);

  // prep: 16*128*128 = 262144 elements -> 1024 blocks
  hipLaunchKernelGGL(prep_kernel, dim3(1024), dim3(256), 0, stream,
                     w_in, w_a, a_param, wTin, wTa, sp8);

  // main: 512 blocks x 512 threads (2 blocks/CU exactly), one head per block
  hipLaunchKernelGGL(rglru_kernel, dim3(512), dim3(512), 0, stream,
                     x, state, b_in, b_a, wTin, wTa, sp8, out);
}